// Round 1
// baseline (57.069 us; speedup 1.0000x reference)
//
#include <hip/hip_runtime.h>

// Reference semantics (DIM=2, S=1, INDEX=(0,), L=12, D=4096, B=128):
//   U = X (Pauli) on wire 0 (most-significant bit of the row index)
//     => out[j] = x[j ^ 2048]  (swap top/bottom halves of the state vector)
//   out = stack([real, imag]) of U @ (x_real + i x_imag)
//     => out[0, j, :] = x_real[j ^ 2048, :]
//        out[1, j, :] = x_imag[j ^ 2048, :]
//
// Pure gather-copy. Row stride B = 128 floats = 32 float4 quads, so the
// XOR-2048 permutation only changes which 512B row we read — every access
// stays fully coalesced. One thread moves one float4 of the real plane and
// the matching float4 of the imag plane (32 B loaded, 32 B stored per lane).

#define D 4096          // 2^L rows
#define B_FLOATS 128    // batch columns
#define QPR 32          // float4 quads per row (128/4)
#define PLANE_QUADS (D * QPR)   // 131072 quads per plane

__global__ __launch_bounds__(256) void x_gate_permute(
    const float4* __restrict__ xr,
    const float4* __restrict__ xi,
    float4* __restrict__ out)
{
    int idx = blockIdx.x * blockDim.x + threadIdx.x;   // quad index in one plane
    int j   = idx >> 5;          // row 0..4095
    int c   = idx & (QPR - 1);   // quad-column 0..31
    int src = ((j ^ 2048) << 5) | c;

    out[idx]               = xr[src];   // real plane
    out[PLANE_QUADS + idx] = xi[src];   // imag plane
}

extern "C" void kernel_launch(void* const* d_in, const int* in_sizes, int n_in,
                              void* d_out, int out_size, void* d_ws, size_t ws_size,
                              hipStream_t stream) {
    const float4* xr = (const float4*)d_in[0];
    const float4* xi = (const float4*)d_in[1];
    float4* out = (float4*)d_out;

    const int threads = 256;
    const int blocks  = PLANE_QUADS / threads;   // 512 blocks
    x_gate_permute<<<blocks, threads, 0, stream>>>(xr, xi, out);
}

// Round 2
// 57.036 us; speedup vs baseline: 1.0006x; 1.0006x over previous
//
#include <hip/hip_runtime.h>

// Reference semantics (DIM=2, S=1, INDEX=(0,), L=12, D=4096, B=128):
//   U = kron(PauliX, I_2048)  =>  out[j] = x[j ^ 2048] (swap vector halves)
//   out[0] = permuted x_real, out[1] = permuted x_imag (M is real: no mixing)
//
// Pure gather-copy: 4 MiB read + 4 MiB write. Row = 128 floats = 32 float4
// quads, so the XOR-2048 row permutation never breaks coalescing.
//
// R1 variant: one float4 load + one float4 store per thread (was two each).
// Blocks 0..511 handle the real plane, 512..1023 the imag plane — the plane
// select is block-uniform, so no lane divergence. This doubles thread-level
// parallelism; if the kernel's device time contributed to dur_us at all,
// this shifts it. Predicted: dur_us unchanged (measurement overhead-bound).

#define D 4096                  // 2^L rows
#define QPR 32                  // float4 quads per row (128 floats / 4)
#define PLANE_QUADS (D * QPR)   // 131072 quads per plane

__global__ __launch_bounds__(256) void x_gate_permute(
    const float4* __restrict__ xr,
    const float4* __restrict__ xi,
    float4* __restrict__ out)
{
    int idx = blockIdx.x * blockDim.x + threadIdx.x;   // 0 .. 2*PLANE_QUADS-1

    // Block-uniform plane select (PLANE_QUADS = 512 blocks * 256 threads).
    const float4* src_plane = (idx < PLANE_QUADS) ? xr : xi;
    int p = idx & (PLANE_QUADS - 1);   // quad index within the plane

    int j = p >> 5;                    // row 0..4095
    int c = p & (QPR - 1);             // quad-column 0..31
    int src = ((j ^ 2048) << 5) | c;   // XOR the MSB of the row index

    out[idx] = src_plane[src];
}

extern "C" void kernel_launch(void* const* d_in, const int* in_sizes, int n_in,
                              void* d_out, int out_size, void* d_ws, size_t ws_size,
                              hipStream_t stream) {
    const float4* xr = (const float4*)d_in[0];
    const float4* xi = (const float4*)d_in[1];
    float4* out = (float4*)d_out;

    const int threads = 256;
    const int blocks  = (2 * PLANE_QUADS) / threads;   // 1024 blocks
    x_gate_permute<<<blocks, threads, 0, stream>>>(xr, xi, out);
}